// Round 1
// baseline (2104.456 us; speedup 1.0000x reference)
//
#include <hip/hip_runtime.h>

typedef unsigned short u16;
typedef unsigned int   u32;

typedef __attribute__((ext_vector_type(8))) short bf16x8;
typedef __attribute__((ext_vector_type(16))) float f32x16;

// ---------- helpers ----------
__device__ __forceinline__ u16 f2bf(float v) {           // RNE fp32 -> bf16
    u32 u = __float_as_uint(v);
    u32 r = (u + 0x7fffu + ((u >> 16) & 1u)) >> 16;
    return (u16)r;
}
__device__ __forceinline__ float bf2f(u16 h) { return __uint_as_float(((u32)h) << 16); }

__device__ __forceinline__ float ftanh(float x) {        // tanh via exp, ~5 inst
    float e = __expf(2.0f * x);                          // inf for large x -> rcp gives 0 -> +1
    return 1.0f - 2.0f * __builtin_amdgcn_rcpf(e + 1.0f);
}

__device__ __forceinline__ void gl2lds16(const void* g, void* l) {
    __builtin_amdgcn_global_load_lds(
        (const __attribute__((address_space(1))) void*)g,
        (__attribute__((address_space(3))) void*)l, 16, 0, 0);
}

// ---------- init: zero h buffers and carry ----------
__global__ void init_k(u16* __restrict__ hh, u16* __restrict__ hl, float* __restrict__ cb) {
    int i = blockIdx.x * 256 + threadIdx.x;           // grid covers 12*512*512
    hh[i] = 0; hl[i] = 0;
    if (i < 2 * 512) cb[i] = 0.0f;
}

// ---------- pack W: W4t[n][k] = W_gate[k][col], hi/lo bf16 split; bias4[n] ----------
__global__ void pack_w(const float* __restrict__ Wf, const float* __restrict__ bf_,
                       const float* __restrict__ Wi, const float* __restrict__ bi_,
                       const float* __restrict__ Wo, const float* __restrict__ bo_,
                       const float* __restrict__ Wg, const float* __restrict__ bg_,
                       u16* __restrict__ wth, u16* __restrict__ wtl, float* __restrict__ bias4) {
    int idx = blockIdx.x * 256 + threadIdx.x;         // 2048*768 threads, wave-uniform n (768=12*64)
    int n = idx / 768, k = idx - n * 768;
    int gate = n >> 9, col = n & 511;
    const float* W = (gate == 0) ? Wf : (gate == 1) ? Wi : (gate == 2) ? Wo : Wg;
    float v = W[k * 512 + col];
    u16 h = f2bf(v);
    wth[idx] = h;
    wtl[idx] = f2bf(v - bf2f(h));
    if (k == 0) {
        const float* bb = (gate == 0) ? bf_ : (gate == 1) ? bi_ : (gate == 2) ? bo_ : bg_;
        bias4[n] = bb[col];
    }
}

// ---------- split ALL x to hi/lo bf16 (hoisted out of the block loop) ----------
__global__ void split_x(const float* __restrict__ src, u16* __restrict__ oh, u16* __restrict__ ol) {
    int i = blockIdx.x * 256 + threadIdx.x;           // grid covers 256*512*256/4
    float4 v = ((const float4*)src)[i];
    u16 hx = f2bf(v.x), hy = f2bf(v.y), hz = f2bf(v.z), hw = f2bf(v.w);
    u16 lx = f2bf(v.x - bf2f(hx)), ly = f2bf(v.y - bf2f(hy));
    u16 lz = f2bf(v.z - bf2f(hz)), lw = f2bf(v.w - bf2f(hw));
    uint2 hv; hv.x = (u32)hx | ((u32)hy << 16); hv.y = (u32)hz | ((u32)hw << 16);
    uint2 lv; lv.x = (u32)lx | ((u32)ly << 16); lv.y = (u32)lz | ((u32)lw << 16);
    ((uint2*)oh)[i] = hv;
    ((uint2*)ol)[i] = lv;
}

// ============================================================================
// Pipelined bf16x3 GEMM, 192x256 tile, BK=32, 8 waves, double-buffered LDS.
//
//   grid = gx*8 blocks (gx = ceil(M/192)); for S=12, gx=32 -> 256 blocks =
//   exactly 1 block/CU (no idle CUs, no tail). XCD swizzle makes XCD i own
//   bn-column i entirely -> its 786 KB W-panel is L2-resident.
//
//   LDS per buffer (q-major chunks): Ah[12ch] Al[12ch] Bh[16ch] Bl[16ch],
//   chunk = 16 rows x 32 K stored as [q=0..3][r=0..15][8 u16] (1 KiB) so a
//   32-lane ds_read_b128 at fixed q spreads uniformly over all banks.
//   global_load_lds writes chunks linearly (lane L -> (r=L&15, q=L>>4)), the
//   global source address is pre-swizzled to match (rule: swizzle both sides).
//
//   Per K-tile (2 phases, template schedule):
//     ph0: stage 4 slots (tile k+1 -> other buf); vmcnt(4)  [= tile-k's 7
//          loads retired, never a full drain mid-loop]; s_barrier; ds_read
//          ks=0 frags; lgkmcnt(0); setprio(1); 18 MFMA; setprio(0); s_barrier
//     ph1: stage 3 slots; ds_read ks=1 frags (buf already published by ph0's
//          barrier); s_barrier; lgkmcnt(0); 18 MFMA; s_barrier
//   Raw asm barriers only -- __syncthreads() would re-insert vmcnt(0) drains.
// ============================================================================
#define KTILES 24
#define BUFHALF 28672   // u16 per buffer: (12+12+16+16)*512

__global__ __launch_bounds__(512, 2) void gemm_p(
    const u16* __restrict__ xh, const u16* __restrict__ xl,
    const u16* __restrict__ hh, const u16* __restrict__ hl,
    const u16* __restrict__ wth, const u16* __restrict__ wtl,
    const float* __restrict__ bias4, float* __restrict__ lg,
    int Mvalid, int gx) {
    __shared__ __align__(16) u16 smem[2 * BUFHALF];   // 112 KiB

    const int tid = threadIdx.x;
    const int wid = tid >> 6, lane = tid & 63;
    const int l32 = lane & 31, khalf = lane >> 5;
    const int wm = wid >> 2, wn = wid & 3;            // 2M x 4N wave grid

    // bijective XCD swizzle (nwg = gx*8 always divisible by 8), bm-fastest:
    // XCD i gets wg in [i*gx, (i+1)*gx) = all bm of one bn column.
    const int wg = (blockIdx.x & 7) * gx + (blockIdx.x >> 3);
    const int bm = wg % gx, bn = wg / gx;

    // ---- staging slots: 56 chunk-loads/K-tile, 7 per wave ----
    const int laneK = (lane >> 4) * 8;                // q*8 u16 within row
    const int lr = lane & 15;                         // row within chunk
    const u16* sp0[7]; const u16* sp1[7]; u32 slds[7]; bool sA[7];
#pragma unroll
    for (int j = 0; j < 7; ++j) {
        int slot = wid * 7 + j;
        int o, c;
        if (slot < 12)      { o = 0; c = slot; }        // Ah
        else if (slot < 24) { o = 1; c = slot - 12; }   // Al
        else if (slot < 40) { o = 2; c = slot - 24; }   // Bh
        else                { o = 3; c = slot - 40; }   // Bl
        if (o < 2) {
            int row = bm * 192 + c * 16 + lr;
            if (row >= Mvalid) row = Mvalid - 1;        // ragged-M clamp (last launch)
            sp0[j] = ((o == 0) ? xh : xl) + (size_t)row * 256 + laneK;   // k < 256
            sp1[j] = ((o == 0) ? hh : hl) + (size_t)row * 512 + laneK;   // k >= 256
            sA[j] = true;
            slds[j] = (o ? 6144u : 0u) + (u32)c * 512u;
        } else {
            int row = bn * 256 + c * 16 + lr;
            sp0[j] = ((o == 2) ? wth : wtl) + (size_t)row * 768 + laneK;
            sp1[j] = sp0[j];
            sA[j] = false;
            slds[j] = ((o == 2) ? 12288u : 20480u) + (u32)c * 512u;
        }
    }

    // ---- fragment read offsets (u16 units); + (ks*2+khalf)*128 per phase ----
    u32 offA[3], offB[2];
#pragma unroll
    for (int i = 0; i < 3; ++i) {
        int r = wm * 96 + i * 32 + l32;
        offA[i] = (u32)((r >> 4) * 512 + (r & 15) * 8);
    }
#pragma unroll
    for (int j = 0; j < 2; ++j) {
        int r = wn * 64 + j * 32 + l32;
        offB[j] = (u32)((r >> 4) * 512 + (r & 15) * 8);
    }

    f32x16 acc[3][2];
#pragma unroll
    for (int i = 0; i < 3; ++i)
#pragma unroll
        for (int j = 0; j < 2; ++j)
#pragma unroll
            for (int r = 0; r < 16; ++r) acc[i][j][r] = 0.f;

    // ---- prologue: stage tile 0 -> buf 0 (k0 = 0, all x/W side) ----
#pragma unroll
    for (int j = 0; j < 7; ++j) gl2lds16(sp0[j], smem + slds[j]);

#pragma unroll 2
    for (int kk = 0; kk < KTILES; ++kk) {
        u16* bufc = smem + (kk & 1) * BUFHALF;
        u16* bufo = smem + ((kk & 1) ^ 1) * BUFHALF;
        const int kn = (kk + 1) * 32;                 // next tile's k0

        // ---------------- phase 0 (ks = 0) ----------------
        if (kk < KTILES - 1) {
#pragma unroll
            for (int j = 0; j < 4; ++j) {
                const u16* src = sA[j] ? ((kn < 256) ? sp0[j] + kn : sp1[j] + (kn - 256))
                                       : (sp0[j] + kn);
                gl2lds16(src, bufo + slds[j]);
            }
            asm volatile("s_waitcnt vmcnt(4)" ::: "memory");  // tile-k's 7 done, 4 newest fly on
        } else {
            asm volatile("s_waitcnt vmcnt(0)" ::: "memory");  // epilogue drain (allowed)
        }
        asm volatile("s_barrier" ::: "memory");               // buf c fully staged, all waves

        bf16x8 ah[3], al[3], bh[2], bl[2];
        {
            const u32 q = (u32)(khalf) * 128u;                // ks=0
#pragma unroll
            for (int i = 0; i < 3; ++i) {
                ah[i] = *(const bf16x8*)(bufc + offA[i] + q);
                al[i] = *(const bf16x8*)(bufc + 6144 + offA[i] + q);
            }
#pragma unroll
            for (int j = 0; j < 2; ++j) {
                bh[j] = *(const bf16x8*)(bufc + 12288 + offB[j] + q);
                bl[j] = *(const bf16x8*)(bufc + 20480 + offB[j] + q);
            }
        }
        asm volatile("s_waitcnt lgkmcnt(0)" ::: "memory");
        __builtin_amdgcn_s_setprio(1);
#pragma unroll
        for (int i = 0; i < 3; ++i)
#pragma unroll
            for (int j = 0; j < 2; ++j) {
                acc[i][j] = __builtin_amdgcn_mfma_f32_32x32x16_bf16(ah[i], bh[j], acc[i][j], 0, 0, 0);
                acc[i][j] = __builtin_amdgcn_mfma_f32_32x32x16_bf16(ah[i], bl[j], acc[i][j], 0, 0, 0);
                acc[i][j] = __builtin_amdgcn_mfma_f32_32x32x16_bf16(al[i], bh[j], acc[i][j], 0, 0, 0);
            }
        __builtin_amdgcn_s_setprio(0);
        asm volatile("s_barrier" ::: "memory");

        // ---------------- phase 1 (ks = 1) ----------------
        if (kk < KTILES - 1) {
#pragma unroll
            for (int j = 4; j < 7; ++j) {
                const u16* src = sA[j] ? ((kn < 256) ? sp0[j] + kn : sp1[j] + (kn - 256))
                                       : (sp0[j] + kn);
                gl2lds16(src, bufo + slds[j]);
            }
        }
        {
            const u32 q = (u32)(2 + khalf) * 128u;            // ks=1 (safe pre-barrier: buf c
#pragma unroll                                                //  was published at ph0's barrier)
            for (int i = 0; i < 3; ++i) {
                ah[i] = *(const bf16x8*)(bufc + offA[i] + q);
                al[i] = *(const bf16x8*)(bufc + 6144 + offA[i] + q);
            }
#pragma unroll
            for (int j = 0; j < 2; ++j) {
                bh[j] = *(const bf16x8*)(bufc + 12288 + offB[j] + q);
                bl[j] = *(const bf16x8*)(bufc + 20480 + offB[j] + q);
            }
        }
        asm volatile("s_barrier" ::: "memory");
        asm volatile("s_waitcnt lgkmcnt(0)" ::: "memory");
        __builtin_amdgcn_s_setprio(1);
#pragma unroll
        for (int i = 0; i < 3; ++i)
#pragma unroll
            for (int j = 0; j < 2; ++j) {
                acc[i][j] = __builtin_amdgcn_mfma_f32_32x32x16_bf16(ah[i], bh[j], acc[i][j], 0, 0, 0);
                acc[i][j] = __builtin_amdgcn_mfma_f32_32x32x16_bf16(ah[i], bl[j], acc[i][j], 0, 0, 0);
                acc[i][j] = __builtin_amdgcn_mfma_f32_32x32x16_bf16(al[i], bh[j], acc[i][j], 0, 0, 0);
            }
        __builtin_amdgcn_s_setprio(0);
        asm volatile("s_barrier" ::: "memory");   // all reads of buf c retired -> next ph0 may restage it
    }

    // C/D layout (measured): col = lane&31, row = (reg&3) + 8*(reg>>2) + 4*(lane>>5)
#pragma unroll
    for (int j = 0; j < 2; ++j) {
        int n = bn * 256 + wn * 64 + j * 32 + l32;
        float bv = bias4[n];
#pragma unroll
        for (int i = 0; i < 3; ++i) {
            int rbase = bm * 192 + wm * 96 + i * 32 + 4 * khalf;
#pragma unroll
            for (int r = 0; r < 16; ++r) {
                int row = rbase + (r & 3) + 8 * (r >> 2);
                if (row < Mvalid)
                    __builtin_nontemporal_store(acc[i][j][r] + bv,
                        &lg[(size_t)row * 2048 + n]);
            }
        }
    }
}

// ---------- one sequential chain step: r <- tanh(softmax_f[rowb]*r + softmax_i[rowb]*tanh(g[rowb])) ----------
__device__ __forceinline__ void chain_step(const float* __restrict__ lg, int j, int lane, float r[8]) {
    int rowb = (j + 1) % 12;   // batch row (t+1)%P of c_t (t0 always multiple of 12)
    const float* base = lg + (size_t)(j * 512 + rowb) * 2048 + lane * 8;
    float f[8], iv[8], g[8];
#pragma unroll
    for (int u = 0; u < 8; ++u) { f[u] = base[u]; iv[u] = base[512 + u]; g[u] = base[1536 + u]; }
    float mf = -1e30f, mi = -1e30f;
#pragma unroll
    for (int u = 0; u < 8; ++u) { mf = fmaxf(mf, f[u]); mi = fmaxf(mi, iv[u]); }
#pragma unroll
    for (int o = 32; o; o >>= 1) { mf = fmaxf(mf, __shfl_xor(mf, o)); mi = fmaxf(mi, __shfl_xor(mi, o)); }
    float sf = 0.f, si = 0.f;
#pragma unroll
    for (int u = 0; u < 8; ++u) {
        f[u] = __expf(f[u] - mf); sf += f[u];
        iv[u] = __expf(iv[u] - mi); si += iv[u];
    }
#pragma unroll
    for (int o = 32; o; o >>= 1) { sf += __shfl_xor(sf, o); si += __shfl_xor(si, o); }
    float rf = __builtin_amdgcn_rcpf(sf), ri = __builtin_amdgcn_rcpf(si);
#pragma unroll
    for (int u = 0; u < 8; ++u) {
        float gg = ftanh(g[u]);
        r[u] = ftanh(f[u] * rf * r[u] + iv[u] * ri * gg);
    }
}

// ---------- gates (chain fused): wave 0 walks chain to its block's s; then all waves do
//            softmax f,i,o + tanh g, c_new, h row (hi/lo bf16), final out ----------
// s reversed vs blockIdx so the longest redundant chains dispatch FIRST and overlap the bulk.
__global__ __launch_bounds__(256) void gates_k(
    const float* __restrict__ lg, float* __restrict__ cb,
    u16* __restrict__ hh, u16* __restrict__ hl,
    float* __restrict__ out, int t0, int S, int rd, int wr) {
    __shared__ float rsh[512];
    const int widx = threadIdx.x >> 6, lane = threadIdx.x & 63;
    const int s = (S - 1) - (blockIdx.x >> 7);          // 128 blocks per s, longest chain first
    const int b = (blockIdx.x & 127) * 4 + widx;
    const int t = t0 + s;

    if (widx == 0) {
        float r[8];
#pragma unroll
        for (int u = 0; u < 8; ++u) r[u] = cb[rd * 512 + lane * 8 + u];
        for (int j = 0; j < s; ++j) chain_step(lg, j, lane, r);   // identical op sequence in every block -> bitwise-identical r
#pragma unroll
        for (int u = 0; u < 8; ++u) rsh[lane * 8 + u] = r[u];
        // carrier block (s == S-1, early dispatch) extends the chain one step, writes next-launch carry
        if ((int)blockIdx.x == 127 && t0 + S < 256) {
            chain_step(lg, S - 1, lane, r);
#pragma unroll
            for (int u = 0; u < 8; ++u) cb[wr * 512 + lane * 8 + u] = r[u];
        }
    }
    __syncthreads();

    const float* row = lg + (size_t)(s * 512 + b) * 2048 + lane * 8;
    float f[8], iv[8], ov[8], g[8];
#pragma unroll
    for (int u = 0; u < 8; ++u) {
        f[u] = row[u]; iv[u] = row[512 + u]; ov[u] = row[1024 + u]; g[u] = row[1536 + u];
    }
    float mf = -1e30f, mi = -1e30f, mo = -1e30f;
#pragma unroll
    for (int u = 0; u < 8; ++u) { mf = fmaxf(mf, f[u]); mi = fmaxf(mi, iv[u]); mo = fmaxf(mo, ov[u]); }
#pragma unroll
    for (int o = 32; o; o >>= 1) {
        mf = fmaxf(mf, __shfl_xor(mf, o));
        mi = fmaxf(mi, __shfl_xor(mi, o));
        mo = fmaxf(mo, __shfl_xor(mo, o));
    }
    float sf = 0.f, si = 0.f, so = 0.f;
#pragma unroll
    for (int u = 0; u < 8; ++u) {
        f[u] = __expf(f[u] - mf); sf += f[u];
        iv[u] = __expf(iv[u] - mi); si += iv[u];
        ov[u] = __expf(ov[u] - mo); so += ov[u];
    }
#pragma unroll
    for (int o = 32; o; o >>= 1) {
        sf += __shfl_xor(sf, o); si += __shfl_xor(si, o); so += __shfl_xor(so, o);
    }
    float rf = __builtin_amdgcn_rcpf(sf), ri = __builtin_amdgcn_rcpf(si), ro = __builtin_amdgcn_rcpf(so);
    float hout[8];
#pragma unroll
    for (int u = 0; u < 8; ++u) {
        float rr = rsh[lane * 8 + u];
        float gg = ftanh(g[u]);
        float cv = ftanh(f[u] * rf * rr + iv[u] * ri * gg);
        hout[u] = ov[u] * ro * cv;
    }
    u32 hhp[4], hlp[4];
#pragma unroll
    for (int u = 0; u < 4; ++u) {
        u16 h0 = f2bf(hout[2 * u]), h1 = f2bf(hout[2 * u + 1]);
        u16 l0 = f2bf(hout[2 * u] - bf2f(h0)), l1 = f2bf(hout[2 * u + 1] - bf2f(h1));
        hhp[u] = (u32)h0 | ((u32)h1 << 16);
        hlp[u] = (u32)l0 | ((u32)l1 << 16);
    }
    size_t hb = ((size_t)(s * 512 + b)) * 512 + lane * 8;   // h row index = t%12 = s
    *(uint4*)&hh[hb] = make_uint4(hhp[0], hhp[1], hhp[2], hhp[3]);
    *(uint4*)&hl[hb] = make_uint4(hlp[0], hlp[1], hlp[2], hlp[3]);
    if (t == 255) {
        float* op = out + (size_t)b * 512 + lane * 8;
#pragma unroll
        for (int u = 0; u < 8; ++u) op[u] = hout[u];
    }
}

extern "C" void kernel_launch(void* const* d_in, const int* in_sizes, int n_in,
                              void* d_out, int out_size, void* d_ws, size_t ws_size,
                              hipStream_t stream) {
    const float* x   = (const float*)d_in[0];
    const float* Wf  = (const float*)d_in[1];
    const float* bf_ = (const float*)d_in[2];
    const float* Wi  = (const float*)d_in[3];
    const float* bi_ = (const float*)d_in[4];
    const float* Wo  = (const float*)d_in[5];
    const float* bo_ = (const float*)d_in[6];
    const float* Wg  = (const float*)d_in[7];
    const float* bg_ = (const float*)d_in[8];
    float* out = (float*)d_out;

    char* p = (char*)d_ws;
    u16* xh  = (u16*)p; p += 134217728;     // [256*512, 256] bf16 hi (full sequence)
    u16* xl  = (u16*)p; p += 134217728;
    u16* wth = (u16*)p; p += 3145728;       // [2048, 768] bf16 hi (transposed W4)
    u16* wtl = (u16*)p; p += 3145728;
    u16* hh  = (u16*)p; p += 6291456;       // [12, 512, 512] bf16 hi
    u16* hl  = (u16*)p; p += 6291456;
    float* bias4 = (float*)p; p += 8192;    // [2048]
    float* cb    = (float*)p; p += 4096;    // [2][512] carry double-buffer
    float* lg    = (float*)p; p += 50331648;// [12*512, 2048] fp32 logits
    // total ~322 MiB (ws poison shows 512 MiB available)

    init_k<<<12288, 256, 0, stream>>>(hh, hl, cb);
    pack_w<<<6144, 256, 0, stream>>>(Wf, bf_, Wi, bi_, Wo, bo_, Wg, bg_, wth, wtl, bias4);
    split_x<<<32768, 256, 0, stream>>>(x, xh, xl);

    for (int blk = 0; blk < 22; ++blk) {
        int t0 = blk * 12;
        int S = (256 - t0 >= 12) ? 12 : (256 - t0);  // last block: 4 steps
        int M = S * 512;
        int gx = (M + 191) / 192;                    // S=12 -> 32 (exact), S=4 -> 11 (ragged)
        gemm_p<<<gx * 8, 512, 0, stream>>>(
            xh + (size_t)t0 * 512 * 256, xl + (size_t)t0 * 512 * 256,
            hh, hl, wth, wtl, bias4, lg, M, gx);
        gates_k<<<S * 128, 256, 0, stream>>>(lg, cb, hh, hl, out, t0, S, blk & 1, (blk + 1) & 1);
    }
}

// Round 2
// 2052.648 us; speedup vs baseline: 1.0252x; 1.0252x over previous
//
#include <hip/hip_runtime.h>

typedef unsigned short u16;
typedef unsigned int   u32;

typedef __attribute__((ext_vector_type(8))) short bf16x8;
typedef __attribute__((ext_vector_type(16))) float f32x16;

// ---------- helpers ----------
__device__ __forceinline__ u16 f2bf(float v) {           // RNE fp32 -> bf16
    u32 u = __float_as_uint(v);
    u32 r = (u + 0x7fffu + ((u >> 16) & 1u)) >> 16;
    return (u16)r;
}
__device__ __forceinline__ float bf2f(u16 h) { return __uint_as_float(((u32)h) << 16); }

__device__ __forceinline__ float ftanh(float x) {        // tanh via exp, ~5 inst
    float e = __expf(2.0f * x);                          // inf for large x -> rcp gives 0 -> +1
    return 1.0f - 2.0f * __builtin_amdgcn_rcpf(e + 1.0f);
}

__device__ __forceinline__ void gl2lds16(const void* g, void* l) {
    __builtin_amdgcn_global_load_lds(
        (const __attribute__((address_space(1))) void*)g,
        (__attribute__((address_space(3))) void*)l, 16, 0, 0);
}

// ---------- init: zero h buffers and carry ----------
__global__ void init_k(u16* __restrict__ hh, u16* __restrict__ hl, float* __restrict__ cb) {
    int i = blockIdx.x * 256 + threadIdx.x;           // grid covers 12*512*512
    hh[i] = 0; hl[i] = 0;
    if (i < 2 * 512) cb[i] = 0.0f;
}

// ---------- pack W' with K'-interleave (K'=2304, 6 segments) + bias4 ----------
// logit = sum over K' of A'(k')*B'(k') where segments give exactly
//   ah*bh + ah*bl + al*bh   (x part, k<256)  and same for h part (k>=256).
// wq[n][j]: j in [0,256)=bh(0:256) | [256,512)=bl(0:256) | [512,768)=bh(0:256)
//           [768,1280)=bh(256:768) | [1280,1792)=bl(256:768) | [1792,2304)=bh(256:768)
__global__ void pack_wq(const float* __restrict__ Wf, const float* __restrict__ bf_,
                        const float* __restrict__ Wi, const float* __restrict__ bi_,
                        const float* __restrict__ Wo, const float* __restrict__ bo_,
                        const float* __restrict__ Wg, const float* __restrict__ bg_,
                        u16* __restrict__ wq, float* __restrict__ bias4) {
    int idx = blockIdx.x * 256 + threadIdx.x;         // 2048*768 threads
    int n = idx / 768, k = idx - n * 768;
    int gate = n >> 9, col = n & 511;
    const float* W = (gate == 0) ? Wf : (gate == 1) ? Wi : (gate == 2) ? Wo : Wg;
    float v = W[k * 512 + col];
    u16 h = f2bf(v);
    u16 l = f2bf(v - bf2f(h));
    size_t base = (size_t)n * 2304;
    if (k < 256) {
        wq[base + k] = h; wq[base + 512 + k] = h; wq[base + 256 + k] = l;
    } else {
        int d = k - 256;
        wq[base + 768 + d] = h; wq[base + 1792 + d] = h; wq[base + 1280 + d] = l;
    }
    if (k == 0) {
        const float* bb = (gate == 0) ? bf_ : (gate == 1) ? bi_ : (gate == 2) ? bo_ : bg_;
        bias4[n] = bb[col];
    }
}

// ---------- split ALL x to hi/lo bf16 (hoisted out of the block loop) ----------
__global__ void split_x(const float* __restrict__ src, u16* __restrict__ oh, u16* __restrict__ ol) {
    int i = blockIdx.x * 256 + threadIdx.x;           // grid covers 256*512*256/4
    float4 v = ((const float4*)src)[i];
    u16 hx = f2bf(v.x), hy = f2bf(v.y), hz = f2bf(v.z), hw = f2bf(v.w);
    u16 lx = f2bf(v.x - bf2f(hx)), ly = f2bf(v.y - bf2f(hy));
    u16 lz = f2bf(v.z - bf2f(hz)), lw = f2bf(v.w - bf2f(hw));
    uint2 hv; hv.x = (u32)hx | ((u32)hy << 16); hv.y = (u32)hz | ((u32)hw << 16);
    uint2 lv; lv.x = (u32)lx | ((u32)ly << 16); lv.y = (u32)lz | ((u32)lw << 16);
    ((uint2*)oh)[i] = hv;
    ((uint2*)ol)[i] = lv;
}

// ============================================================================
// Standard bf16 GEMM over K'=2304. BM=192, BN=256, BK=64, 512 thr (2Mx4N waves).
// grid = gx*8 (gx=32 full rounds -> 256 blocks = 1/CU exactly).
// XCD rect: xcd = bid&7 owns bm in [4*xcd, 4*xcd+4) x all bn  -> A read ONCE
// per XCD (~19MB/round total), W' slices L2/L3-resident.
// LDS 136 KiB: A triple-buffered (24KB, depth-2 prefetch covers HBM latency),
// B double-buffered (32KB, depth-1, L2-resident W').
// Per K-tile: issue B(kt+1); vmcnt(7) [exactly tile-kt's 7 loads retired,
// never 0 mid-loop]; barrier; reads+12 MFMA; issue A(kt+2); reads+12 MFMA;
// barrier. LDS rows XOR-swizzled via pre-swizzled GLOBAL source (dest linear
// for global_load_lds); read with same XOR -> conflict-free ds_read_b128.
// ============================================================================
#define KT 36
__global__ __launch_bounds__(512, 2) void gemm_q(
    const u16* __restrict__ xh, const u16* __restrict__ xl,
    const u16* __restrict__ hh, const u16* __restrict__ hl,
    const u16* __restrict__ wq, const float* __restrict__ bias4,
    float* __restrict__ lg, int Mvalid, int gx) {
    __shared__ __align__(16) u16 smem[69632];   // A:3x12288 | B:2x16384 (136 KiB)

    const int tid = threadIdx.x;
    const int wid = tid >> 6, lane = tid & 63;
    const int l32 = lane & 31, khalf = lane >> 5;
    const int wm = wid >> 2, wn = wid & 3;

    int bm, bn;
    if (gx == 32) { int xcd = blockIdx.x & 7, r = blockIdx.x >> 3; bm = xcd * 4 + (r & 3); bn = r >> 2; }
    else          { bm = blockIdx.x % gx; bn = blockIdx.x / gx; }

    const int lr8 = lane >> 3;                        // row within 8-row chunk
    const int ksw = ((lane & 7) ^ (lr8 & 7)) * 8;     // pre-swizzled elem offset

    int arowc[3]; size_t brow[4];
#pragma unroll
    for (int c = 0; c < 3; ++c) {
        int row = bm * 192 + (wid * 3 + c) * 8 + lr8;
        if (row >= Mvalid) row = Mvalid - 1;          // ragged-M clamp (last launch)
        arowc[c] = row;
    }
#pragma unroll
    for (int c = 0; c < 4; ++c)
        brow[c] = (size_t)(bn * 256 + (wid * 4 + c) * 8 + lr8) * 2304;

#define STAGE_A(kt, dstoff) do {                                              \
        int kt_ = (kt); const u16* base_; int str_, ko_;                      \
        if (kt_ < 12) { base_ = (kt_ >= 8) ? xl : xh; str_ = 256; ko_ = (kt_ & 3) * 64; } \
        else { int sub_ = kt_ - 12; base_ = (sub_ >= 16) ? hl : hh; str_ = 512; ko_ = (sub_ & 7) * 64; } \
        _Pragma("unroll")                                                     \
        for (int c_ = 0; c_ < 3; ++c_)                                        \
            gl2lds16(base_ + (size_t)arowc[c_] * str_ + ko_ + ksw,            \
                     smem + (dstoff) + (wid * 3 + c_) * 512 + lane * 8);      \
    } while (0)

#define STAGE_B(kt, dstoff) do {                                              \
        _Pragma("unroll")                                                     \
        for (int c_ = 0; c_ < 4; ++c_)                                        \
            gl2lds16(wq + brow[c_] + (kt) * 64 + ksw,                         \
                     smem + (dstoff) + (wid * 4 + c_) * 512 + lane * 8);      \
    } while (0)

    // fragment LDS offsets (u16 units), [tile][ks]; swizzle folded in
    u32 offA[3][4], offB[2][4];
#pragma unroll
    for (int i = 0; i < 3; ++i) {
        int row = wm * 96 + i * 32 + l32;
        u32 rsw = (u32)(row & 7) << 3;
#pragma unroll
        for (int ks = 0; ks < 4; ++ks)
            offA[i][ks] = (u32)row * 64 + (((u32)(ks * 16 + khalf * 8)) ^ rsw);
    }
#pragma unroll
    for (int j = 0; j < 2; ++j) {
        int row = wn * 64 + j * 32 + l32;
        u32 rsw = (u32)(row & 7) << 3;
#pragma unroll
        for (int ks = 0; ks < 4; ++ks)
            offB[j][ks] = (u32)row * 64 + (((u32)(ks * 16 + khalf * 8)) ^ rsw);
    }

    f32x16 acc[3][2];
#pragma unroll
    for (int i = 0; i < 3; ++i)
#pragma unroll
        for (int j = 0; j < 2; ++j)
#pragma unroll
            for (int r = 0; r < 16; ++r) acc[i][j][r] = 0.f;

    // prologue: A depth-2, B depth-1
    STAGE_A(0, 0);
    STAGE_B(0, 36864);
    STAGE_A(1, 12288);

    int aoff = 0;                                     // A buf offset for tile kt
    for (int kt = 0; kt < KT; ++kt) {
        const int boff = 36864 + ((kt & 1) << 14);
        if (kt + 1 < KT) {
            STAGE_B(kt + 1, 36864 + (((kt + 1) & 1) << 14));
            asm volatile("s_waitcnt vmcnt(7)" ::: "memory");   // retires tile-kt's 7
        } else {
            asm volatile("s_waitcnt vmcnt(0)" ::: "memory");   // epilogue drain
        }
        __builtin_amdgcn_s_barrier();
        __builtin_amdgcn_sched_barrier(0);

        const u16* At = smem + aoff;
        const u16* Bt = smem + boff;

        // ---- half 0 (ks 0,1) ----
        bf16x8 a0[3][2], b0[2][2];
#pragma unroll
        for (int i = 0; i < 3; ++i)
#pragma unroll
            for (int ks = 0; ks < 2; ++ks) a0[i][ks] = *(const bf16x8*)(At + offA[i][ks]);
#pragma unroll
        for (int j = 0; j < 2; ++j)
#pragma unroll
            for (int ks = 0; ks < 2; ++ks) b0[j][ks] = *(const bf16x8*)(Bt + offB[j][ks]);
        __builtin_amdgcn_s_setprio(1);
#pragma unroll
        for (int ks = 0; ks < 2; ++ks)
#pragma unroll
            for (int i = 0; i < 3; ++i)
#pragma unroll
                for (int j = 0; j < 2; ++j)
                    acc[i][j] = __builtin_amdgcn_mfma_f32_32x32x16_bf16(a0[i][ks], b0[j][ks], acc[i][j], 0, 0, 0);
        __builtin_amdgcn_s_setprio(0);

        // stage A two tiles ahead (HBM-latency depth-2)
        if (kt + 2 < KT) {
            int adst = aoff + 24576; if (adst >= 36864) adst -= 36864;
            STAGE_A(kt + 2, adst);
        }

        // ---- half 1 (ks 2,3) ----
        bf16x8 a1[3][2], b1[2][2];
#pragma unroll
        for (int i = 0; i < 3; ++i)
#pragma unroll
            for (int ks = 0; ks < 2; ++ks) a1[i][ks] = *(const bf16x8*)(At + offA[i][ks + 2]);
#pragma unroll
        for (int j = 0; j < 2; ++j)
#pragma unroll
            for (int ks = 0; ks < 2; ++ks) b1[j][ks] = *(const bf16x8*)(Bt + offB[j][ks + 2]);
        __builtin_amdgcn_s_setprio(1);
#pragma unroll
        for (int ks = 0; ks < 2; ++ks)
#pragma unroll
            for (int i = 0; i < 3; ++i)
#pragma unroll
                for (int j = 0; j < 2; ++j)
                    acc[i][j] = __builtin_amdgcn_mfma_f32_32x32x16_bf16(a1[i][ks], b1[j][ks], acc[i][j], 0, 0, 0);
        __builtin_amdgcn_s_setprio(0);

        __builtin_amdgcn_s_barrier();                 // all reads of tile-kt bufs retired
        __builtin_amdgcn_sched_barrier(0);
        aoff += 12288; if (aoff == 36864) aoff = 0;
    }
#undef STAGE_A
#undef STAGE_B

    // C/D layout (measured): col = lane&31, row = (reg&3) + 8*(reg>>2) + 4*(lane>>5)
#pragma unroll
    for (int j = 0; j < 2; ++j) {
        int n = bn * 256 + wn * 64 + j * 32 + l32;
        float bv = bias4[n];
#pragma unroll
        for (int i = 0; i < 3; ++i) {
            int rbase = bm * 192 + wm * 96 + i * 32 + 4 * khalf;
#pragma unroll
            for (int r = 0; r < 16; ++r) {
                int row = rbase + (r & 3) + 8 * (r >> 2);
                if (row < Mvalid)
                    lg[(size_t)row * 2048 + n] = acc[i][j][r] + bv;   // via L2/L3 (gates re-reads)
            }
        }
    }
}

// ---------- one sequential chain step: r <- tanh(softmax_f[rowb]*r + softmax_i[rowb]*tanh(g[rowb])) ----------
__device__ __forceinline__ void chain_step(const float* __restrict__ lg, int j, int lane, float r[8]) {
    int rowb = (j + 1) % 12;   // batch row (t+1)%P of c_t (t0 always multiple of 12)
    const float* base = lg + (size_t)(j * 512 + rowb) * 2048 + lane * 8;
    float f[8], iv[8], g[8];
#pragma unroll
    for (int u = 0; u < 8; ++u) { f[u] = base[u]; iv[u] = base[512 + u]; g[u] = base[1536 + u]; }
    float mf = -1e30f, mi = -1e30f;
#pragma unroll
    for (int u = 0; u < 8; ++u) { mf = fmaxf(mf, f[u]); mi = fmaxf(mi, iv[u]); }
#pragma unroll
    for (int o = 32; o; o >>= 1) { mf = fmaxf(mf, __shfl_xor(mf, o)); mi = fmaxf(mi, __shfl_xor(mi, o)); }
    float sf = 0.f, si = 0.f;
#pragma unroll
    for (int u = 0; u < 8; ++u) {
        f[u] = __expf(f[u] - mf); sf += f[u];
        iv[u] = __expf(iv[u] - mi); si += iv[u];
    }
#pragma unroll
    for (int o = 32; o; o >>= 1) { sf += __shfl_xor(sf, o); si += __shfl_xor(si, o); }
    float rf = __builtin_amdgcn_rcpf(sf), ri = __builtin_amdgcn_rcpf(si);
#pragma unroll
    for (int u = 0; u < 8; ++u) {
        float gg = ftanh(g[u]);
        r[u] = ftanh(f[u] * rf * r[u] + iv[u] * ri * gg);
    }
}

// ---------- gates (chain fused): wave 0 walks chain to its block's s; then all waves do
//            softmax f,i,o + tanh g, c_new, h row (hi/lo bf16), final out ----------
// s reversed vs blockIdx so the longest redundant chains dispatch FIRST and overlap the bulk.
__global__ __launch_bounds__(256) void gates_k(
    const float* __restrict__ lg, float* __restrict__ cb,
    u16* __restrict__ hh, u16* __restrict__ hl,
    float* __restrict__ out, int t0, int S, int rd, int wr) {
    __shared__ float rsh[512];
    const int widx = threadIdx.x >> 6, lane = threadIdx.x & 63;
    const int s = (S - 1) - (blockIdx.x >> 7);          // 128 blocks per s, longest chain first
    const int b = (blockIdx.x & 127) * 4 + widx;
    const int t = t0 + s;

    if (widx == 0) {
        float r[8];
#pragma unroll
        for (int u = 0; u < 8; ++u) r[u] = cb[rd * 512 + lane * 8 + u];
        for (int j = 0; j < s; ++j) chain_step(lg, j, lane, r);   // identical op sequence in every block -> bitwise-identical r
#pragma unroll
        for (int u = 0; u < 8; ++u) rsh[lane * 8 + u] = r[u];
        // carrier block (s == S-1, early dispatch) extends the chain one step, writes next-launch carry
        if ((int)blockIdx.x == 127 && t0 + S < 256) {
            chain_step(lg, S - 1, lane, r);
#pragma unroll
            for (int u = 0; u < 8; ++u) cb[wr * 512 + lane * 8 + u] = r[u];
        }
    }
    __syncthreads();

    const float* row = lg + (size_t)(s * 512 + b) * 2048 + lane * 8;
    float f[8], iv[8], ov[8], g[8];
#pragma unroll
    for (int u = 0; u < 8; ++u) {
        f[u] = row[u]; iv[u] = row[512 + u]; ov[u] = row[1024 + u]; g[u] = row[1536 + u];
    }
    float mf = -1e30f, mi = -1e30f, mo = -1e30f;
#pragma unroll
    for (int u = 0; u < 8; ++u) { mf = fmaxf(mf, f[u]); mi = fmaxf(mi, iv[u]); mo = fmaxf(mo, ov[u]); }
#pragma unroll
    for (int o = 32; o; o >>= 1) {
        mf = fmaxf(mf, __shfl_xor(mf, o));
        mi = fmaxf(mi, __shfl_xor(mi, o));
        mo = fmaxf(mo, __shfl_xor(mo, o));
    }
    float sf = 0.f, si = 0.f, so = 0.f;
#pragma unroll
    for (int u = 0; u < 8; ++u) {
        f[u] = __expf(f[u] - mf); sf += f[u];
        iv[u] = __expf(iv[u] - mi); si += iv[u];
        ov[u] = __expf(ov[u] - mo); so += ov[u];
    }
#pragma unroll
    for (int o = 32; o; o >>= 1) {
        sf += __shfl_xor(sf, o); si += __shfl_xor(si, o); so += __shfl_xor(so, o);
    }
    float rf = __builtin_amdgcn_rcpf(sf), ri = __builtin_amdgcn_rcpf(si), ro = __builtin_amdgcn_rcpf(so);
    float hout[8];
#pragma unroll
    for (int u = 0; u < 8; ++u) {
        float rr = rsh[lane * 8 + u];
        float gg = ftanh(g[u]);
        float cv = ftanh(f[u] * rf * rr + iv[u] * ri * gg);
        hout[u] = ov[u] * ro * cv;
    }
    u32 hhp[4], hlp[4];
#pragma unroll
    for (int u = 0; u < 4; ++u) {
        u16 h0 = f2bf(hout[2 * u]), h1 = f2bf(hout[2 * u + 1]);
        u16 l0 = f2bf(hout[2 * u] - bf2f(h0)), l1 = f2bf(hout[2 * u + 1] - bf2f(h1));
        hhp[u] = (u32)h0 | ((u32)h1 << 16);
        hlp[u] = (u32)l0 | ((u32)l1 << 16);
    }
    size_t hb = ((size_t)(s * 512 + b)) * 512 + lane * 8;   // h row index = t%12 = s
    *(uint4*)&hh[hb] = make_uint4(hhp[0], hhp[1], hhp[2], hhp[3]);
    *(uint4*)&hl[hb] = make_uint4(hlp[0], hlp[1], hlp[2], hlp[3]);
    if (t == 255) {
        float* op = out + (size_t)b * 512 + lane * 8;
#pragma unroll
        for (int u = 0; u < 8; ++u) op[u] = hout[u];
    }
}

extern "C" void kernel_launch(void* const* d_in, const int* in_sizes, int n_in,
                              void* d_out, int out_size, void* d_ws, size_t ws_size,
                              hipStream_t stream) {
    const float* x   = (const float*)d_in[0];
    const float* Wf  = (const float*)d_in[1];
    const float* bf_ = (const float*)d_in[2];
    const float* Wi  = (const float*)d_in[3];
    const float* bi_ = (const float*)d_in[4];
    const float* Wo  = (const float*)d_in[5];
    const float* bo_ = (const float*)d_in[6];
    const float* Wg  = (const float*)d_in[7];
    const float* bg_ = (const float*)d_in[8];
    float* out = (float*)d_out;

    char* p = (char*)d_ws;
    u16* xh  = (u16*)p; p += 134217728;     // [256*512, 256] bf16 hi (full sequence)
    u16* xl  = (u16*)p; p += 134217728;
    u16* wq  = (u16*)p; p += 9437184;       // [2048, 2304] K'-interleaved W'
    u16* hh  = (u16*)p; p += 6291456;       // [12, 512, 512] bf16 hi
    u16* hl  = (u16*)p; p += 6291456;
    float* bias4 = (float*)p; p += 8192;    // [2048]
    float* cb    = (float*)p; p += 4096;    // [2][512] carry double-buffer
    float* lg    = (float*)p; p += 50331648;// [12*512, 2048] fp32 logits
    // total ~341 MiB (ws poison shows 512 MiB available)

    init_k<<<12288, 256, 0, stream>>>(hh, hl, cb);
    pack_wq<<<6144, 256, 0, stream>>>(Wf, bf_, Wi, bi_, Wo, bo_, Wg, bg_, wq, bias4);
    split_x<<<32768, 256, 0, stream>>>(x, xh, xl);

    for (int blk = 0; blk < 22; ++blk) {
        int t0 = blk * 12;
        int S = (256 - t0 >= 12) ? 12 : (256 - t0);  // last block: 4 steps
        int M = S * 512;
        int gx = (M + 191) / 192;                    // S=12 -> 32 (exact), S=4 -> 11 (ragged)
        gemm_q<<<gx * 8, 512, 0, stream>>>(
            xh + (size_t)t0 * 512 * 256, xl + (size_t)t0 * 512 * 256,
            hh, hl, wq, bias4, lg, M, gx);
        gates_k<<<S * 128, 256, 0, stream>>>(lg, cb, hh, hl, out, t0, S, blk & 1, (blk + 1) & 1);
    }
}

// Round 3
// 1988.259 us; speedup vs baseline: 1.0584x; 1.0324x over previous
//
#include <hip/hip_runtime.h>

typedef unsigned short u16;
typedef unsigned int   u32;

typedef __attribute__((ext_vector_type(8))) short bf16x8;
typedef __attribute__((ext_vector_type(16))) float f32x16;

// ---------- helpers ----------
__device__ __forceinline__ u16 f2bf(float v) {           // RNE fp32 -> bf16
    u32 u = __float_as_uint(v);
    u32 r = (u + 0x7fffu + ((u >> 16) & 1u)) >> 16;
    return (u16)r;
}
__device__ __forceinline__ float bf2f(u16 h) { return __uint_as_float(((u32)h) << 16); }

__device__ __forceinline__ float ftanh(float x) {        // tanh via exp, ~5 inst
    float e = __expf(2.0f * x);                          // inf for large x -> rcp gives 0 -> +1
    return 1.0f - 2.0f * __builtin_amdgcn_rcpf(e + 1.0f);
}

__device__ __forceinline__ void gl2lds16(const void* g, void* l) {
    __builtin_amdgcn_global_load_lds(
        (const __attribute__((address_space(1))) void*)g,
        (__attribute__((address_space(3))) void*)l, 16, 0, 0);
}

// ---------- init: zero h buffers and carry ----------
__global__ void init_k(u16* __restrict__ hh, u16* __restrict__ hl, float* __restrict__ cb) {
    int i = blockIdx.x * 256 + threadIdx.x;           // grid covers 12*512*512
    hh[i] = 0; hl[i] = 0;
    if (i < 2 * 512) cb[i] = 0.0f;
}

// ---------- pack W' with K'-interleave (K'=2304, 6 segments) + bias4 ----------
// logit = sum over K' of A'(k')*B'(k') where segments give exactly
//   ah*bh + ah*bl + al*bh   (x part, k<256)  and same for h part (k>=256).
__global__ void pack_wq(const float* __restrict__ Wf, const float* __restrict__ bf_,
                        const float* __restrict__ Wi, const float* __restrict__ bi_,
                        const float* __restrict__ Wo, const float* __restrict__ bo_,
                        const float* __restrict__ Wg, const float* __restrict__ bg_,
                        u16* __restrict__ wq, float* __restrict__ bias4) {
    int idx = blockIdx.x * 256 + threadIdx.x;         // 2048*768 threads
    int n = idx / 768, k = idx - n * 768;
    int gate = n >> 9, col = n & 511;
    const float* W = (gate == 0) ? Wf : (gate == 1) ? Wi : (gate == 2) ? Wo : Wg;
    float v = W[k * 512 + col];
    u16 h = f2bf(v);
    u16 l = f2bf(v - bf2f(h));
    size_t base = (size_t)n * 2304;
    if (k < 256) {
        wq[base + k] = h; wq[base + 512 + k] = h; wq[base + 256 + k] = l;
    } else {
        int d = k - 256;
        wq[base + 768 + d] = h; wq[base + 1792 + d] = h; wq[base + 1280 + d] = l;
    }
    if (k == 0) {
        const float* bb = (gate == 0) ? bf_ : (gate == 1) ? bi_ : (gate == 2) ? bo_ : bg_;
        bias4[n] = bb[col];
    }
}

// ---------- split ALL x to hi/lo bf16 (hoisted out of the block loop) ----------
__global__ void split_x(const float* __restrict__ src, u16* __restrict__ oh, u16* __restrict__ ol) {
    int i = blockIdx.x * 256 + threadIdx.x;           // grid covers 256*512*256/4
    float4 v = ((const float4*)src)[i];
    u16 hx = f2bf(v.x), hy = f2bf(v.y), hz = f2bf(v.z), hw = f2bf(v.w);
    u16 lx = f2bf(v.x - bf2f(hx)), ly = f2bf(v.y - bf2f(hy));
    u16 lz = f2bf(v.z - bf2f(hz)), lw = f2bf(v.w - bf2f(hw));
    uint2 hv; hv.x = (u32)hx | ((u32)hy << 16); hv.y = (u32)hz | ((u32)hw << 16);
    uint2 lv; lv.x = (u32)lx | ((u32)ly << 16); lv.y = (u32)lz | ((u32)lw << 16);
    ((uint2*)oh)[i] = hv;
    ((uint2*)ol)[i] = lv;
}

// ============================================================================
// bf16 GEMM over K'=2304, BM=192 BN=256 BK=64, 512 thr (2Mx4N waves), grid gx*8.
// FINE-PHASE schedule (m201 port): each K-tile = 4 phases (one 16-wide k-step).
//   phase p: { 5 ds_read_b128 (3A+2B, ks=p) | 1-2 global_load_lds staging |
//              barrier | 6 independent MFMA (one per acc tile) | barrier }
// Single publish point per tile: end-of-tile vmcnt(3) keeps A(kt+2) in flight,
// retires B(kt+1)+A(kt+1); barrier then publishes buf kt+1. Reads of phases
// 1..3 issue pre-barrier against the already-published buffer; sched_barrier(0)
// after each s_barrier stops cross-phase hoisting. Staging spread 2/2/2/1 so
// global-load latency spans ~4 phases. A triple-buffered, B double-buffered.
// ============================================================================
#define KT 36
__global__ __launch_bounds__(512, 2) void gemm_q(
    const u16* __restrict__ xh, const u16* __restrict__ xl,
    const u16* __restrict__ hh, const u16* __restrict__ hl,
    const u16* __restrict__ wq, const float* __restrict__ bias4,
    float* __restrict__ lg, int Mvalid, int gx) {
    __shared__ __align__(16) u16 smem[69632];   // A:3x12288 | B:2x16384 (136 KiB)

    const int tid = threadIdx.x;
    const int wid = tid >> 6, lane = tid & 63;
    const int l32 = lane & 31, khalf = lane >> 5;
    const int wm = wid >> 2, wn = wid & 3;

    int bm, bn;
    if (gx == 32) { int xcd = blockIdx.x & 7, r = blockIdx.x >> 3; bm = xcd * 4 + (r & 3); bn = r >> 2; }
    else          { bm = blockIdx.x % gx; bn = blockIdx.x / gx; }

    const int lr8 = lane >> 3;                        // row within 8-row chunk
    const int ksw = ((lane & 7) ^ (lr8 & 7)) * 8;     // pre-swizzled elem offset

    int arowc[3]; size_t brow[4];
#pragma unroll
    for (int c = 0; c < 3; ++c) {
        int row = bm * 192 + (wid * 3 + c) * 8 + lr8;
        if (row >= Mvalid) row = Mvalid - 1;          // ragged-M clamp (last launch)
        arowc[c] = row;
    }
#pragma unroll
    for (int c = 0; c < 4; ++c)
        brow[c] = (size_t)(bn * 256 + (wid * 4 + c) * 8 + lr8) * 2304;

    // stage A chunks [c0, c0+nc) of tile kt into A-buf at dstoff
#define STAGE_A(kt, dstoff, c0, nc) do {                                      \
        int kt_ = (kt); const u16* base_; int str_, ko_;                      \
        if (kt_ < 12) { base_ = (kt_ >= 8) ? xl : xh; str_ = 256; ko_ = (kt_ & 3) * 64; } \
        else { int sub_ = kt_ - 12; base_ = (sub_ >= 16) ? hl : hh; str_ = 512; ko_ = (sub_ & 7) * 64; } \
        _Pragma("unroll")                                                     \
        for (int c_ = (c0); c_ < (c0) + (nc); ++c_)                           \
            gl2lds16(base_ + (size_t)arowc[c_] * str_ + ko_ + ksw,            \
                     smem + (dstoff) + (wid * 3 + c_) * 512 + lane * 8);      \
    } while (0)

#define STAGE_B(kt, dstoff, c0, nc) do {                                      \
        _Pragma("unroll")                                                     \
        for (int c_ = (c0); c_ < (c0) + (nc); ++c_)                           \
            gl2lds16(wq + brow[c_] + (kt) * 64 + ksw,                         \
                     smem + (dstoff) + (wid * 4 + c_) * 512 + lane * 8);      \
    } while (0)

    // fragment LDS offsets (u16 units), [tile][ks]; swizzle folded in
    u32 offA[3][4], offB[2][4];
#pragma unroll
    for (int i = 0; i < 3; ++i) {
        int row = wm * 96 + i * 32 + l32;
        u32 rsw = (u32)(row & 7) << 3;
#pragma unroll
        for (int ks = 0; ks < 4; ++ks)
            offA[i][ks] = (u32)row * 64 + (((u32)(ks * 16 + khalf * 8)) ^ rsw);
    }
#pragma unroll
    for (int j = 0; j < 2; ++j) {
        int row = wn * 64 + j * 32 + l32;
        u32 rsw = (u32)(row & 7) << 3;
#pragma unroll
        for (int ks = 0; ks < 4; ++ks)
            offB[j][ks] = (u32)row * 64 + (((u32)(ks * 16 + khalf * 8)) ^ rsw);
    }

    f32x16 acc[3][2];
#pragma unroll
    for (int i = 0; i < 3; ++i)
#pragma unroll
        for (int j = 0; j < 2; ++j)
#pragma unroll
            for (int r = 0; r < 16; ++r) acc[i][j][r] = 0.f;

    // prologue: A depth-2, B depth-1; publish buf 0 (keep A(1) in flight)
    STAGE_A(0, 0, 0, 3);
    STAGE_B(0, 36864, 0, 4);
    STAGE_A(1, 12288, 0, 3);
    asm volatile("s_waitcnt vmcnt(3)" ::: "memory");
    __builtin_amdgcn_s_barrier();
    __builtin_amdgcn_sched_barrier(0);

#pragma unroll 6
    for (int kt = 0; kt < KT; ++kt) {
        const u16* At = smem + (kt % 3) * 12288;
        const u16* Bt = smem + 36864 + (kt & 1) * 16384;
        const int bdst = 36864 + (((kt + 1) & 1) << 14);
        const int adst = ((kt + 2) % 3) * 12288;

#pragma unroll
        for (int p = 0; p < 4; ++p) {
            // ds-reads for this phase (buffer already published)
            bf16x8 a[3], b[2];
#pragma unroll
            for (int i = 0; i < 3; ++i) a[i] = *(const bf16x8*)(At + offA[i][p]);
#pragma unroll
            for (int j = 0; j < 2; ++j) b[j] = *(const bf16x8*)(Bt + offB[j][p]);
            // staging spread across phases: B(kt+1) in p0/p1, A(kt+2) in p2/p3
            if (p == 0 && kt + 1 < KT) STAGE_B(kt + 1, bdst, 0, 2);
            if (p == 1 && kt + 1 < KT) STAGE_B(kt + 1, bdst, 2, 2);
            if (p == 2 && kt + 2 < KT) STAGE_A(kt + 2, adst, 0, 2);
            if (p == 3 && kt + 2 < KT) STAGE_A(kt + 2, adst, 2, 1);

            __builtin_amdgcn_s_barrier();
            __builtin_amdgcn_sched_barrier(0);

            __builtin_amdgcn_s_setprio(1);
#pragma unroll
            for (int i = 0; i < 3; ++i)
#pragma unroll
                for (int j = 0; j < 2; ++j)
                    acc[i][j] = __builtin_amdgcn_mfma_f32_32x32x16_bf16(a[i], b[j], acc[i][j], 0, 0, 0);
            __builtin_amdgcn_s_setprio(0);

            if (p < 3) {
                __builtin_amdgcn_s_barrier();
                __builtin_amdgcn_sched_barrier(0);
            }
        }

        // end of tile: publish buf kt+1 (retire B(kt+1)+A(kt+1); keep A(kt+2))
        if (kt < KT - 2) asm volatile("s_waitcnt vmcnt(3)" ::: "memory");
        else             asm volatile("s_waitcnt vmcnt(0)" ::: "memory");
        __builtin_amdgcn_s_barrier();
        __builtin_amdgcn_sched_barrier(0);
    }
#undef STAGE_A
#undef STAGE_B

    // C/D layout (measured): col = lane&31, row = (reg&3) + 8*(reg>>2) + 4*(lane>>5)
#pragma unroll
    for (int j = 0; j < 2; ++j) {
        int n = bn * 256 + wn * 64 + j * 32 + l32;
        float bv = bias4[n];
#pragma unroll
        for (int i = 0; i < 3; ++i) {
            int rbase = bm * 192 + wm * 96 + i * 32 + 4 * khalf;
#pragma unroll
            for (int r = 0; r < 16; ++r) {
                int row = rbase + (r & 3) + 8 * (r >> 2);
                if (row < Mvalid)
                    lg[(size_t)row * 2048 + n] = acc[i][j][r] + bv;   // via L2/L3 (gates re-reads)
            }
        }
    }
}

// ---------- one sequential chain step: r <- tanh(softmax_f[rowb]*r + softmax_i[rowb]*tanh(g[rowb])) ----------
__device__ __forceinline__ void chain_step(const float* __restrict__ lg, int j, int lane, float r[8]) {
    int rowb = (j + 1) % 12;   // batch row (t+1)%P of c_t (t0 always multiple of 12)
    const float* base = lg + (size_t)(j * 512 + rowb) * 2048 + lane * 8;
    float f[8], iv[8], g[8];
#pragma unroll
    for (int u = 0; u < 8; ++u) { f[u] = base[u]; iv[u] = base[512 + u]; g[u] = base[1536 + u]; }
    float mf = -1e30f, mi = -1e30f;
#pragma unroll
    for (int u = 0; u < 8; ++u) { mf = fmaxf(mf, f[u]); mi = fmaxf(mi, iv[u]); }
#pragma unroll
    for (int o = 32; o; o >>= 1) { mf = fmaxf(mf, __shfl_xor(mf, o)); mi = fmaxf(mi, __shfl_xor(mi, o)); }
    float sf = 0.f, si = 0.f;
#pragma unroll
    for (int u = 0; u < 8; ++u) {
        f[u] = __expf(f[u] - mf); sf += f[u];
        iv[u] = __expf(iv[u] - mi); si += iv[u];
    }
#pragma unroll
    for (int o = 32; o; o >>= 1) { sf += __shfl_xor(sf, o); si += __shfl_xor(si, o); }
    float rf = __builtin_amdgcn_rcpf(sf), ri = __builtin_amdgcn_rcpf(si);
#pragma unroll
    for (int u = 0; u < 8; ++u) {
        float gg = ftanh(g[u]);
        r[u] = ftanh(f[u] * rf * r[u] + iv[u] * ri * gg);
    }
}

// ---------- gates (chain fused): wave 0 walks chain to its block's s; then all waves do
//            softmax f,i,o + tanh g, c_new, h row (hi/lo bf16), final out ----------
__global__ __launch_bounds__(256) void gates_k(
    const float* __restrict__ lg, float* __restrict__ cb,
    u16* __restrict__ hh, u16* __restrict__ hl,
    float* __restrict__ out, int t0, int S, int rd, int wr) {
    __shared__ float rsh[512];
    const int widx = threadIdx.x >> 6, lane = threadIdx.x & 63;
    const int s = (S - 1) - (blockIdx.x >> 7);          // 128 blocks per s, longest chain first
    const int b = (blockIdx.x & 127) * 4 + widx;
    const int t = t0 + s;

    if (widx == 0) {
        float r[8];
#pragma unroll
        for (int u = 0; u < 8; ++u) r[u] = cb[rd * 512 + lane * 8 + u];
        for (int j = 0; j < s; ++j) chain_step(lg, j, lane, r);   // identical op sequence in every block -> bitwise-identical r
#pragma unroll
        for (int u = 0; u < 8; ++u) rsh[lane * 8 + u] = r[u];
        // carrier block (s == S-1, early dispatch) extends the chain one step, writes next-launch carry
        if ((int)blockIdx.x == 127 && t0 + S < 256) {
            chain_step(lg, S - 1, lane, r);
#pragma unroll
            for (int u = 0; u < 8; ++u) cb[wr * 512 + lane * 8 + u] = r[u];
        }
    }
    __syncthreads();

    const float* row = lg + (size_t)(s * 512 + b) * 2048 + lane * 8;
    float f[8], iv[8], ov[8], g[8];
#pragma unroll
    for (int u = 0; u < 8; ++u) {
        f[u] = row[u]; iv[u] = row[512 + u]; ov[u] = row[1024 + u]; g[u] = row[1536 + u];
    }
    float mf = -1e30f, mi = -1e30f, mo = -1e30f;
#pragma unroll
    for (int u = 0; u < 8; ++u) { mf = fmaxf(mf, f[u]); mi = fmaxf(mi, iv[u]); mo = fmaxf(mo, ov[u]); }
#pragma unroll
    for (int o = 32; o; o >>= 1) {
        mf = fmaxf(mf, __shfl_xor(mf, o));
        mi = fmaxf(mi, __shfl_xor(mi, o));
        mo = fmaxf(mo, __shfl_xor(mo, o));
    }
    float sf = 0.f, si = 0.f, so = 0.f;
#pragma unroll
    for (int u = 0; u < 8; ++u) {
        f[u] = __expf(f[u] - mf); sf += f[u];
        iv[u] = __expf(iv[u] - mi); si += iv[u];
        ov[u] = __expf(ov[u] - mo); so += ov[u];
    }
#pragma unroll
    for (int o = 32; o; o >>= 1) {
        sf += __shfl_xor(sf, o); si += __shfl_xor(si, o); so += __shfl_xor(so, o);
    }
    float rf = __builtin_amdgcn_rcpf(sf), ri = __builtin_amdgcn_rcpf(si), ro = __builtin_amdgcn_rcpf(so);
    float hout[8];
#pragma unroll
    for (int u = 0; u < 8; ++u) {
        float rr = rsh[lane * 8 + u];
        float gg = ftanh(g[u]);
        float cv = ftanh(f[u] * rf * rr + iv[u] * ri * gg);
        hout[u] = ov[u] * ro * cv;
    }
    u32 hhp[4], hlp[4];
#pragma unroll
    for (int u = 0; u < 4; ++u) {
        u16 h0 = f2bf(hout[2 * u]), h1 = f2bf(hout[2 * u + 1]);
        u16 l0 = f2bf(hout[2 * u] - bf2f(h0)), l1 = f2bf(hout[2 * u + 1] - bf2f(h1));
        hhp[u] = (u32)h0 | ((u32)h1 << 16);
        hlp[u] = (u32)l0 | ((u32)l1 << 16);
    }
    size_t hb = ((size_t)(s * 512 + b)) * 512 + lane * 8;   // h row index = t%12 = s
    *(uint4*)&hh[hb] = make_uint4(hhp[0], hhp[1], hhp[2], hhp[3]);
    *(uint4*)&hl[hb] = make_uint4(hlp[0], hlp[1], hlp[2], hlp[3]);
    if (t == 255) {
        float* op = out + (size_t)b * 512 + lane * 8;
#pragma unroll
        for (int u = 0; u < 8; ++u) op[u] = hout[u];
    }
}

extern "C" void kernel_launch(void* const* d_in, const int* in_sizes, int n_in,
                              void* d_out, int out_size, void* d_ws, size_t ws_size,
                              hipStream_t stream) {
    const float* x   = (const float*)d_in[0];
    const float* Wf  = (const float*)d_in[1];
    const float* bf_ = (const float*)d_in[2];
    const float* Wi  = (const float*)d_in[3];
    const float* bi_ = (const float*)d_in[4];
    const float* Wo  = (const float*)d_in[5];
    const float* bo_ = (const float*)d_in[6];
    const float* Wg  = (const float*)d_in[7];
    const float* bg_ = (const float*)d_in[8];
    float* out = (float*)d_out;

    char* p = (char*)d_ws;
    u16* xh  = (u16*)p; p += 134217728;     // [256*512, 256] bf16 hi (full sequence)
    u16* xl  = (u16*)p; p += 134217728;
    u16* wq  = (u16*)p; p += 9437184;       // [2048, 2304] K'-interleaved W'
    u16* hh  = (u16*)p; p += 6291456;       // [12, 512, 512] bf16 hi
    u16* hl  = (u16*)p; p += 6291456;
    float* bias4 = (float*)p; p += 8192;    // [2048]
    float* cb    = (float*)p; p += 4096;    // [2][512] carry double-buffer
    float* lg    = (float*)p; p += 50331648;// [12*512, 2048] fp32 logits
    // total ~341 MiB (ws poison shows 512 MiB available)

    init_k<<<12288, 256, 0, stream>>>(hh, hl, cb);
    pack_wq<<<6144, 256, 0, stream>>>(Wf, bf_, Wi, bi_, Wo, bo_, Wg, bg_, wq, bias4);
    split_x<<<32768, 256, 0, stream>>>(x, xh, xl);

    for (int blk = 0; blk < 22; ++blk) {
        int t0 = blk * 12;
        int S = (256 - t0 >= 12) ? 12 : (256 - t0);  // last block: 4 steps
        int M = S * 512;
        int gx = (M + 191) / 192;                    // S=12 -> 32 (exact), S=4 -> 11 (ragged)
        gemm_q<<<gx * 8, 512, 0, stream>>>(
            xh + (size_t)t0 * 512 * 256, xl + (size_t)t0 * 512 * 256,
            hh, hl, wq, bias4, lg, M, gx);
        gates_k<<<S * 128, 256, 0, stream>>>(lg, cb, hh, hl, out, t0, S, blk & 1, (blk + 1) & 1);
    }
}